// Round 3
// baseline (281.582 us; speedup 1.0000x reference)
//
#include <hip/hip_runtime.h>
#include <hip/hip_bf16.h>

#define N_NODES 100000
#define N_EDGES 800000
#define IN_DIM  128
#define HIDDEN  128
#define CLASSES 40
#define CAP     32          // max degree supported (Poisson(8): P(>32) ~ 3e-11/node)
#define NSH     8           // shards == XCDs
#define SLICES  100
#define EPB     8000        // edges per slice (SLICES*EPB == N_EDGES)
#define BIN_B   (NSH*SLICES)  // 800 binning blocks: blk&7 = shard, blk>>3 = slice
#define CAST_B  12500       // 100000*32/256
#define PACK_B  24          // (4096+2048)/256
#define CUR_STRIDE 12544    // per-shard counter stride (ints, 16-aligned -> shard-pure lines)

typedef __attribute__((ext_vector_type(8))) short bf16x8;
typedef __attribute__((ext_vector_type(4))) float floatx4;

__device__ __forceinline__ float bf2f(unsigned short u) {
    return __uint_as_float(((unsigned int)u) << 16);
}
__device__ __forceinline__ unsigned short f2bf(float f) {
    unsigned int u = __float_as_uint(f);
    unsigned int r = 0x7fffu + ((u >> 16) & 1u);   // RNE
    return (unsigned short)((u + r) >> 16);
}
__device__ __forceinline__ int curIdx(int d) { return (d & 7) * CUR_STRIDE + (d >> 3); }

// ================= prep: bin + cast_x + pack1 + pack2 in one launch =================
// Binning is XCD-sharded: block (blk&7) only bins edges with (dst&7)==shard, and
// blockIdx%8 round-robins onto XCDs -> cur/csr lines stay in ONE XCD's L2
// (local atomics, write-merged csr lines). Correctness does not depend on the mapping.
__global__ void k_prep(const int* __restrict__ src, const int* __restrict__ dst,
                       int* __restrict__ cur, int* __restrict__ csr,
                       const float* __restrict__ x, unsigned short* __restrict__ A1,
                       const float* __restrict__ W1l, const float* __restrict__ W1r,
                       unsigned short* __restrict__ Bp1,
                       const float* __restrict__ W2l, const float* __restrict__ W2r,
                       unsigned short* __restrict__ Bp2) {
    int blk = blockIdx.x;
    if (blk < BIN_B) {
        int g = blk & 7;            // shard (== XCD up to constant rotation)
        int slice = blk >> 3;
        const int4* s4p = reinterpret_cast<const int4*>(src) + slice * (EPB / 4);
        const int4* d4p = reinterpret_cast<const int4*>(dst) + slice * (EPB / 4);
        for (int i = threadIdx.x; i < EPB / 4; i += 256) {
            int4 d4 = d4p[i];
            int4 s4 = s4p[i];
            #pragma unroll
            for (int j = 0; j < 4; ++j) {
                int d = (&d4.x)[j];
                if ((d & 7) == g) {
                    int s = (&s4.x)[j];
                    int slot = atomicAdd(&cur[g * CUR_STRIDE + (d >> 3)], 1);
                    if (slot < CAP) csr[d * CAP + slot] = s;
                }
            }
        }
    } else if (blk < BIN_B + CAST_B) {
        // ---- x f32 -> bf16 into A1 cols 128..255 ----
        int t = (blk - BIN_B) * 256 + threadIdx.x;
        int n = t >> 5, g = t & 31;
        float4 v = reinterpret_cast<const float4*>(x + (size_t)n * 128)[g];
        ushort4 u = { f2bf(v.x), f2bf(v.y), f2bf(v.z), f2bf(v.w) };
        *(ushort4*)(A1 + (size_t)n * 256 + 128 + g * 4) = u;
    } else {
        int t = (blk - BIN_B - CAST_B) * 256 + threadIdx.x;
        if (t < 4096) {
            // ---- pack W1l/W1r -> Bp1[o 0..31][n 0..127][8] ----
            int o = t >> 7, n = t & 127;
            const float* W = (o < 16) ? W1l : W1r;
            int k0 = (o & 15) * 8;
            union { unsigned short us[8]; uint4 v; } pk;
            #pragma unroll
            for (int j = 0; j < 8; ++j) pk.us[j] = f2bf(W[(size_t)(k0 + j) * 128 + n]);
            *(uint4*)(Bp1 + (size_t)t * 8) = pk.v;
        } else {
            // ---- pack W2l/W2r -> Bp2[o 0..15][n 0..127][8]: n<64 W2l, n>=64 W2r ----
            int t2 = t - 4096;
            int o = t2 >> 7, n = t2 & 127;
            const float* W = (n < 64) ? W2l : W2r;
            int col = n & 63;
            int k0 = o * 8;
            union { unsigned short us[8]; uint4 v; } pk;
            #pragma unroll
            for (int j = 0; j < 8; ++j)
                pk.us[j] = (col < 40) ? f2bf(W[(size_t)(k0 + j) * 40 + col]) : (unsigned short)0;
            *(uint4*)(Bp2 + (size_t)t2 * 8) = pk.v;
        }
    }
}

// ===== fused: gather-mean (2 nodes/wave-step, 8 loads in flight) + MFMA GEMMs =====
// Wave wv owns output rows m0..m0+15; it gathers those nodes' means into the
// wave-local LDS tile S[wv], then phase A reads A-fragments kt<4 from LDS
// (mean) and kt>=4 from global (x). No barriers: S is [wv]-sliced, per-wave DS
// ops are in-order. Phase B writes P (bf16, A1 bytes 0..127) + R (f32, Rbuf) --
// both disjoint from the x-half (bytes 256..511) other blocks still gather.
__global__ __launch_bounds__(256)
void k_fused(unsigned short* __restrict__ A1, float* __restrict__ Rbuf,
             const int* __restrict__ deg, const int* __restrict__ csr,
             const unsigned short* __restrict__ Bp1, const float* __restrict__ b1,
             const unsigned short* __restrict__ Bp2) {
    __shared__ unsigned short S[4][16][136];   // mean tile, then reused as H tile
    int wv = threadIdx.x >> 6, lane = threadIdx.x & 63;
    int q = lane >> 4, nn = lane & 15;
    int m0 = blockIdx.x * 64 + wv * 16;

    // ---- gather phase: 16 nodes, processed 2 at a time ----
    for (int i = 0; i < 16; i += 2) {
        int nA = m0 + i, nB = m0 + i + 1;
        int aA = min(nA, N_NODES - 1), aB = min(nB, N_NODES - 1);
        int cntA = (nA < N_NODES) ? min(deg[curIdx(aA)], CAP) : 0;
        int cntB = (nB < N_NODES) ? min(deg[curIdx(aB)], CAP) : 0;
        int nl = csr[(lane < 32 ? aA : aB) * CAP + (lane & 31)];
        float accA[8] = {}, accB[8] = {};
        int mx = max(cntA, cntB);
        for (int b = 0; b < mx; b += 16) {
            #pragma unroll
            for (int u = 0; u < 4; ++u) {
                int e = b + u * 4 + q;
                int iA = min(e, cntA - 1) & 31;
                int iB = min(e, cntB - 1) & 31;
                int sA = __shfl(nl, iA, 64);            // list A lives in lanes 0..31
                int sB = __shfl(nl, 32 + iB, 64);       // list B lives in lanes 32..63
                bf16x8 vA = {}, vB = {};
                if (e < cntA) vA = *(const bf16x8*)(A1 + (size_t)sA * 256 + 128 + nn * 8);
                if (e < cntB) vB = *(const bf16x8*)(A1 + (size_t)sB * 256 + 128 + nn * 8);
                #pragma unroll
                for (int j = 0; j < 8; ++j) {
                    accA[j] += bf2f((unsigned short)vA[j]);
                    accB[j] += bf2f((unsigned short)vB[j]);
                }
            }
        }
        #pragma unroll
        for (int j = 0; j < 8; ++j) {
            accA[j] += __shfl_xor(accA[j], 16, 64);
            accA[j] += __shfl_xor(accA[j], 32, 64);
            accB[j] += __shfl_xor(accB[j], 16, 64);
            accB[j] += __shfl_xor(accB[j], 32, 64);
        }
        if (lane < 16) {
            float invA = 1.0f / fmaxf((float)cntA, 1.0f);
            float invB = 1.0f / fmaxf((float)cntB, 1.0f);
            union { unsigned short us[8]; bf16x8 v; } pA, pB;
            #pragma unroll
            for (int j = 0; j < 8; ++j) {
                pA.us[j] = f2bf(accA[j] * invA);
                pB.us[j] = f2bf(accB[j] * invB);
            }
            *(bf16x8*)(&S[wv][i][lane * 8])     = pA.v;
            *(bf16x8*)(&S[wv][i + 1][lane * 8]) = pB.v;
        }
    }

    int ma = m0 + nn;
    bool mv = (ma < N_NODES);
    const unsigned short* arow = A1 + (size_t)ma * 256;

    // phase A: [mean|x] @ Bp1, K=256 (mean from LDS, x from global)
    floatx4 acc[8] = {};
    #pragma unroll
    for (int kt = 0; kt < 8; ++kt) {
        bf16x8 a;
        if (kt < 4) {
            a = *(const bf16x8*)(&S[wv][nn][kt * 32 + q * 8]);
        } else {
            a = bf16x8{};
            if (mv) a = *(const bf16x8*)(arow + kt * 32 + q * 8);
        }
        bf16x8 b[8];
        #pragma unroll
        for (int nt = 0; nt < 8; ++nt)
            b[nt] = *(const bf16x8*)(Bp1 + ((size_t)((kt * 4 + q) * 128 + nt * 16 + nn)) * 8);
        #pragma unroll
        for (int nt = 0; nt < 8; ++nt)
            acc[nt] = __builtin_amdgcn_mfma_f32_16x16x32_bf16(a, b[nt], acc[nt], 0, 0, 0);
    }
    // epilogue A: relu + bias -> LDS (reuse S as H tile; wave-local, in-order DS)
    #pragma unroll
    for (int nt = 0; nt < 8; ++nt) {
        int col = nt * 16 + nn;
        float bias = b1[col];
        #pragma unroll
        for (int r = 0; r < 4; ++r)
            S[wv][q * 4 + r][col] = f2bf(fmaxf(acc[nt][r] + bias, 0.f));
    }
    // phase B: h @ Bp2, K=128 -> P (cols 0..63) | R (cols 64..127)
    floatx4 acc2[8] = {};
    #pragma unroll
    for (int kt = 0; kt < 4; ++kt) {
        bf16x8 a = *(const bf16x8*)(&S[wv][nn][kt * 32 + q * 8]);
        bf16x8 b[8];
        #pragma unroll
        for (int nt = 0; nt < 8; ++nt)
            b[nt] = *(const bf16x8*)(Bp2 + ((size_t)((kt * 4 + q) * 128 + nt * 16 + nn)) * 8);
        #pragma unroll
        for (int nt = 0; nt < 8; ++nt)
            acc2[nt] = __builtin_amdgcn_mfma_f32_16x16x32_bf16(a, b[nt], acc2[nt], 0, 0, 0);
    }
    // epilogue B: P bf16 -> A1 cols 0..63; R f32 -> Rbuf (x-half stays live for gathers)
    #pragma unroll
    for (int nt = 0; nt < 4; ++nt) {
        int col = nt * 16 + nn;
        #pragma unroll
        for (int r = 0; r < 4; ++r) {
            int ro = m0 + q * 4 + r;
            if (ro < N_NODES)
                A1[(size_t)ro * 256 + col] = f2bf(acc2[nt][r]);
        }
    }
    #pragma unroll
    for (int nt = 4; nt < 8; ++nt) {
        int col = (nt - 4) * 16 + nn;
        #pragma unroll
        for (int r = 0; r < 4; ++r) {
            int ro = m0 + q * 4 + r;
            if (ro < N_NODES)
                Rbuf[(size_t)ro * 64 + col] = acc2[nt][r];
        }
    }
}

// ================= gather-mean layer 2 (2 nodes/wave) + fused output =================
__global__ void k_agg2(const unsigned short* __restrict__ A1, const float* __restrict__ Rbuf,
                       const int* __restrict__ deg, const int* __restrict__ csr,
                       const float* __restrict__ b2, float* __restrict__ out) {
    int pair = blockIdx.x * 4 + (threadIdx.x >> 6);
    int nA = pair * 2, nB = nA + 1;
    int lane = threadIdx.x & 63;
    if (nA >= N_NODES) return;
    int aB = min(nB, N_NODES - 1);
    int cntA = min(deg[curIdx(nA)], CAP);
    int cntB = (nB < N_NODES) ? min(deg[curIdx(aB)], CAP) : 0;
    int nl = csr[(lane < 32 ? nA : aB) * CAP + (lane & 31)];
    int r = lane >> 3, c = lane & 7;
    float accA[8] = {}, accB[8] = {};
    int mx = max(cntA, cntB);
    for (int b = 0; b < mx; b += 16) {
        #pragma unroll
        for (int u = 0; u < 2; ++u) {
            int e = b + u * 8 + r;
            int sA = __shfl(nl, min(e, cntA - 1) & 31, 64);
            int sB = __shfl(nl, 32 + (min(e, cntB - 1) & 31), 64);
            bf16x8 vA = {}, vB = {};
            if (e < cntA) vA = *(const bf16x8*)(A1 + (size_t)sA * 256 + c * 8);
            if (e < cntB) vB = *(const bf16x8*)(A1 + (size_t)sB * 256 + c * 8);
            #pragma unroll
            for (int j = 0; j < 8; ++j) {
                accA[j] += bf2f((unsigned short)vA[j]);
                accB[j] += bf2f((unsigned short)vB[j]);
            }
        }
    }
    #pragma unroll
    for (int j = 0; j < 8; ++j) {
        accA[j] += __shfl_xor(accA[j], 8, 64);
        accA[j] += __shfl_xor(accA[j], 16, 64);
        accA[j] += __shfl_xor(accA[j], 32, 64);
        accB[j] += __shfl_xor(accB[j], 8, 64);
        accB[j] += __shfl_xor(accB[j], 16, 64);
        accB[j] += __shfl_xor(accB[j], 32, 64);
    }
    if (lane < 5) {   // cols c*8..c*8+7, all < 40
        float invA = 1.0f / fmaxf((float)cntA, 1.0f);
        const float* RrowA = Rbuf + (size_t)nA * 64;
        float o[8];
        #pragma unroll
        for (int j = 0; j < 8; ++j)
            o[j] = accA[j] * invA + RrowA[c * 8 + j] + b2[c * 8 + j];
        float* opA = out + (size_t)nA * CLASSES + c * 8;
        *(float4*)(opA)     = make_float4(o[0], o[1], o[2], o[3]);
        *(float4*)(opA + 4) = make_float4(o[4], o[5], o[6], o[7]);
        if (nB < N_NODES) {
            float invB = 1.0f / fmaxf((float)cntB, 1.0f);
            const float* RrowB = Rbuf + (size_t)nB * 64;
            #pragma unroll
            for (int j = 0; j < 8; ++j)
                o[j] = accB[j] * invB + RrowB[c * 8 + j] + b2[c * 8 + j];
            float* opB = out + (size_t)nB * CLASSES + c * 8;
            *(float4*)(opB)     = make_float4(o[0], o[1], o[2], o[3]);
            *(float4*)(opB + 4) = make_float4(o[4], o[5], o[6], o[7]);
        }
    }
}

extern "C" void kernel_launch(void* const* d_in, const int* in_sizes, int n_in,
                              void* d_out, int out_size, void* d_ws, size_t ws_size,
                              hipStream_t stream) {
    const float* x   = (const float*)d_in[0];
    const int*   ei  = (const int*)d_in[1];
    const float* W1l = (const float*)d_in[2];
    const float* W1r = (const float*)d_in[3];
    const float* b1  = (const float*)d_in[4];
    const float* W2l = (const float*)d_in[5];
    const float* W2r = (const float*)d_in[6];
    const float* b2  = (const float*)d_in[7];
    float* out = (float*)d_out;

    const int* src = ei;
    const int* dst = ei + N_EDGES;

    char* ws = (char*)d_ws;
    size_t off = 0;
    auto alloc = [&](size_t bytes) { void* p = ws + off; off += (bytes + 511) & ~(size_t)511; return p; };
    int* cur = (int*)alloc((size_t)NSH * CUR_STRIDE * 4);              // sharded degree/cursor
    int* csr = (int*)alloc((size_t)N_NODES * CAP * 4);                 // padded CSR (12.8 MB)
    unsigned short* Bp1 = (unsigned short*)alloc((size_t)32 * 128 * 8 * 2);
    unsigned short* Bp2 = (unsigned short*)alloc((size_t)16 * 128 * 8 * 2);
    unsigned short* A1  = (unsigned short*)alloc((size_t)N_NODES * 256 * 2);  // [P|..|x]
    float* Rbuf = (float*)alloc((size_t)N_NODES * 64 * 4);             // x@W2r (25.6 MB)

    hipMemsetAsync(cur, 0, (size_t)NSH * CUR_STRIDE * 4, stream);

    k_prep<<<BIN_B + CAST_B + PACK_B, 256, 0, stream>>>(
        src, dst, cur, csr, x, A1, W1l, W1r, Bp1, W2l, W2r, Bp2);

    k_fused<<<(N_NODES + 63) / 64, 256, 0, stream>>>(A1, Rbuf, cur, csr, Bp1, b1, Bp2);
    k_agg2<<<(N_NODES / 2 + 3) / 4, 256, 0, stream>>>(A1, Rbuf, cur, csr, b2, out);
}

// Round 4
// 270.162 us; speedup vs baseline: 1.0423x; 1.0423x over previous
//
#include <hip/hip_runtime.h>
#include <hip/hip_bf16.h>

#define N_NODES 100000
#define N_EDGES 800000
#define IN_DIM  128
#define HIDDEN  128
#define CLASSES 40
#define CAP     32          // max degree supported (Poisson(8): P(>32) ~ 3e-11/node)
#define NSH     8           // shards == XCDs
#define SLICES  400
#define EPB     2000        // edges per slice (SLICES*EPB == N_EDGES)
#define BIN_B   (NSH*SLICES)  // 3200 binning blocks: blk&7 = shard, blk>>3 = slice
#define CAST_B  12500       // 100000*32/256
#define PACK_B  24          // (4096+2048)/256
#define CUR_STRIDE 12544    // per-shard counter stride (ints, 16-aligned -> shard-pure lines)

typedef __attribute__((ext_vector_type(8))) short bf16x8;
typedef __attribute__((ext_vector_type(4))) float floatx4;

__device__ __forceinline__ float bf2f(unsigned short u) {
    return __uint_as_float(((unsigned int)u) << 16);
}
__device__ __forceinline__ unsigned short f2bf(float f) {
    unsigned int u = __float_as_uint(f);
    unsigned int r = 0x7fffu + ((u >> 16) & 1u);   // RNE
    return (unsigned short)((u + r) >> 16);
}
__device__ __forceinline__ int curIdx(int d) { return (d & 7) * CUR_STRIDE + (d >> 3); }

// ================= prep: bin + cast_x + pack1 + pack2 in one launch =================
// Binning is XCD-sharded: block (blk&7) only bins edges with (dst&7)==shard, and
// blockIdx%8 round-robins onto XCDs -> cur/csr lines stay in ONE XCD's L2
// (local atomics, write-merged csr lines). Correctness does not depend on the mapping.
// 400 slices: short per-thread atomic chains; edge re-reads are L3-served.
__global__ void k_prep(const int* __restrict__ src, const int* __restrict__ dst,
                       int* __restrict__ cur, int* __restrict__ csr,
                       const float* __restrict__ x, unsigned short* __restrict__ A1,
                       const float* __restrict__ W1l, const float* __restrict__ W1r,
                       unsigned short* __restrict__ Bp1,
                       const float* __restrict__ W2l, const float* __restrict__ W2r,
                       unsigned short* __restrict__ Bp2) {
    int blk = blockIdx.x;
    if (blk < BIN_B) {
        int g = blk & 7;            // shard (== XCD up to constant rotation)
        int slice = blk >> 3;
        const int4* s4p = reinterpret_cast<const int4*>(src) + slice * (EPB / 4);
        const int4* d4p = reinterpret_cast<const int4*>(dst) + slice * (EPB / 4);
        for (int i = threadIdx.x; i < EPB / 4; i += 256) {
            int4 d4 = d4p[i];
            int4 s4 = s4p[i];
            #pragma unroll
            for (int j = 0; j < 4; ++j) {
                int d = (&d4.x)[j];
                if ((d & 7) == g) {
                    int s = (&s4.x)[j];
                    int slot = atomicAdd(&cur[g * CUR_STRIDE + (d >> 3)], 1);
                    if (slot < CAP) csr[d * CAP + slot] = s;
                }
            }
        }
    } else if (blk < BIN_B + CAST_B) {
        // ---- x f32 -> bf16 into A1 cols 128..255 ----
        int t = (blk - BIN_B) * 256 + threadIdx.x;
        int n = t >> 5, g = t & 31;
        float4 v = reinterpret_cast<const float4*>(x + (size_t)n * 128)[g];
        ushort4 u = { f2bf(v.x), f2bf(v.y), f2bf(v.z), f2bf(v.w) };
        *(ushort4*)(A1 + (size_t)n * 256 + 128 + g * 4) = u;
    } else {
        int t = (blk - BIN_B - CAST_B) * 256 + threadIdx.x;
        if (t < 4096) {
            // ---- pack W1l/W1r -> Bp1[o 0..31][n 0..127][8] ----
            int o = t >> 7, n = t & 127;
            const float* W = (o < 16) ? W1l : W1r;
            int k0 = (o & 15) * 8;
            union { unsigned short us[8]; uint4 v; } pk;
            #pragma unroll
            for (int j = 0; j < 8; ++j) pk.us[j] = f2bf(W[(size_t)(k0 + j) * 128 + n]);
            *(uint4*)(Bp1 + (size_t)t * 8) = pk.v;
        } else {
            // ---- pack W2l/W2r -> Bp2[o 0..15][n 0..127][8]: n<64 W2l, n>=64 W2r ----
            int t2 = t - 4096;
            int o = t2 >> 7, n = t2 & 127;
            const float* W = (n < 64) ? W2l : W2r;
            int col = n & 63;
            int k0 = o * 8;
            union { unsigned short us[8]; uint4 v; } pk;
            #pragma unroll
            for (int j = 0; j < 8; ++j)
                pk.us[j] = (col < 40) ? f2bf(W[(size_t)(k0 + j) * 40 + col]) : (unsigned short)0;
            *(uint4*)(Bp2 + (size_t)t2 * 8) = pk.v;
        }
    }
}

// ================= gather-mean layer 1: 2 nodes/wave, 8 gathers in flight ==========
// Lists for nodes nA/nB live in lane halves 0..31 / 32..63; shfl is whole-wave
// (hoisted out of the divergent load) so EXEC=0-source hazards never arise.
__global__ void k_agg1(unsigned short* __restrict__ A1, const int* __restrict__ deg,
                       const int* __restrict__ csr) {
    int pair = blockIdx.x * 4 + (threadIdx.x >> 6);
    int nA = pair * 2, nB = nA + 1;
    int lane = threadIdx.x & 63;
    if (nA >= N_NODES) return;
    int aB = min(nB, N_NODES - 1);
    int cntA = min(deg[curIdx(nA)], CAP);
    int cntB = (nB < N_NODES) ? min(deg[curIdx(aB)], CAP) : 0;
    int nl = csr[(lane < 32 ? nA : aB) * CAP + (lane & 31)];
    int q = lane >> 4, c = lane & 15;
    float accA[8] = {}, accB[8] = {};
    int mx = max(cntA, cntB);
    for (int b = 0; b < mx; b += 16) {
        #pragma unroll
        for (int u = 0; u < 4; ++u) {
            int e = b + u * 4 + q;
            int sA = __shfl(nl, min(e, cntA - 1) & 31, 64);
            int sB = __shfl(nl, 32 + (min(e, cntB - 1) & 31), 64);
            bf16x8 vA = {}, vB = {};
            if (e < cntA) vA = *(const bf16x8*)(A1 + (size_t)sA * 256 + 128 + c * 8);
            if (e < cntB) vB = *(const bf16x8*)(A1 + (size_t)sB * 256 + 128 + c * 8);
            #pragma unroll
            for (int j = 0; j < 8; ++j) {
                accA[j] += bf2f((unsigned short)vA[j]);
                accB[j] += bf2f((unsigned short)vB[j]);
            }
        }
    }
    #pragma unroll
    for (int j = 0; j < 8; ++j) {
        accA[j] += __shfl_xor(accA[j], 16, 64);
        accA[j] += __shfl_xor(accA[j], 32, 64);
        accB[j] += __shfl_xor(accB[j], 16, 64);
        accB[j] += __shfl_xor(accB[j], 32, 64);
    }
    if (lane < 16) {
        float invA = 1.0f / fmaxf((float)cntA, 1.0f);
        float invB = 1.0f / fmaxf((float)cntB, 1.0f);
        union { unsigned short us[8]; bf16x8 v; } pA, pB;
        #pragma unroll
        for (int j = 0; j < 8; ++j) {
            pA.us[j] = f2bf(accA[j] * invA);
            pB.us[j] = f2bf(accB[j] * invB);
        }
        *(bf16x8*)(A1 + (size_t)nA * 256 + c * 8) = pA.v;
        if (nB < N_NODES)
            *(bf16x8*)(A1 + (size_t)nB * 256 + c * 8) = pB.v;
    }
}

// ================= fused MFMA: h=relu([mean|x]@Wp1+b1); P|R = h@Wp2 =================
__global__ __launch_bounds__(256)
void k_gemm(unsigned short* __restrict__ A1, const unsigned short* __restrict__ Bp1,
            const float* __restrict__ b1, const unsigned short* __restrict__ Bp2) {
    __shared__ unsigned short Hs[4][16][136];
    int wv = threadIdx.x >> 6, lane = threadIdx.x & 63;
    int q = lane >> 4, nn = lane & 15;
    int m0 = blockIdx.x * 64 + wv * 16;
    int ma = m0 + nn;
    bool mv = (ma < N_NODES);
    const unsigned short* arow = A1 + (size_t)ma * 256;

    // phase A: [mean|x] @ Bp1, K=256
    floatx4 acc[8] = {};
    for (int kt = 0; kt < 8; ++kt) {
        bf16x8 a = {};
        if (mv) a = *(const bf16x8*)(arow + kt * 32 + q * 8);
        bf16x8 b[8];
        #pragma unroll
        for (int nt = 0; nt < 8; ++nt)
            b[nt] = *(const bf16x8*)(Bp1 + ((size_t)((kt * 4 + q) * 128 + nt * 16 + nn)) * 8);
        #pragma unroll
        for (int nt = 0; nt < 8; ++nt)
            acc[nt] = __builtin_amdgcn_mfma_f32_16x16x32_bf16(a, b[nt], acc[nt], 0, 0, 0);
    }
    // epilogue A: relu + bias -> LDS (wave-local tile; per-wave DS ops are in-order)
    #pragma unroll
    for (int nt = 0; nt < 8; ++nt) {
        int col = nt * 16 + nn;
        float bias = b1[col];
        #pragma unroll
        for (int r = 0; r < 4; ++r)
            Hs[wv][q * 4 + r][col] = f2bf(fmaxf(acc[nt][r] + bias, 0.f));
    }
    // phase B: h @ Bp2, K=128 -> P (cols 0..63) | R (cols 64..127)
    floatx4 acc2[8] = {};
    for (int kt = 0; kt < 4; ++kt) {
        bf16x8 a = *(const bf16x8*)(&Hs[wv][nn][kt * 32 + q * 8]);
        bf16x8 b[8];
        #pragma unroll
        for (int nt = 0; nt < 8; ++nt)
            b[nt] = *(const bf16x8*)(Bp2 + ((size_t)((kt * 4 + q) * 128 + nt * 16 + nn)) * 8);
        #pragma unroll
        for (int nt = 0; nt < 8; ++nt)
            acc2[nt] = __builtin_amdgcn_mfma_f32_16x16x32_bf16(a, b[nt], acc2[nt], 0, 0, 0);
    }
    // epilogue B: P bf16 cols 0..63; R f32 at byte offset 256 of each 512B row
    #pragma unroll
    for (int nt = 0; nt < 4; ++nt) {
        int col = nt * 16 + nn;
        #pragma unroll
        for (int r = 0; r < 4; ++r) {
            int ro = m0 + q * 4 + r;
            if (ro < N_NODES)
                A1[(size_t)ro * 256 + col] = f2bf(acc2[nt][r]);
        }
    }
    #pragma unroll
    for (int nt = 4; nt < 8; ++nt) {
        int col = (nt - 4) * 16 + nn;
        #pragma unroll
        for (int r = 0; r < 4; ++r) {
            int ro = m0 + q * 4 + r;
            if (ro < N_NODES) {
                float* Rp = (float*)(A1 + (size_t)ro * 256 + 128);
                Rp[col] = acc2[nt][r];
            }
        }
    }
}

// ========== gather-mean layer 2: 2 nodes/wave, 4 gathers in flight + output ==========
__global__ void k_agg2(const unsigned short* __restrict__ A1, const int* __restrict__ deg,
                       const int* __restrict__ csr, const float* __restrict__ b2,
                       float* __restrict__ out) {
    int pair = blockIdx.x * 4 + (threadIdx.x >> 6);
    int nA = pair * 2, nB = nA + 1;
    int lane = threadIdx.x & 63;
    if (nA >= N_NODES) return;
    int aB = min(nB, N_NODES - 1);
    int cntA = min(deg[curIdx(nA)], CAP);
    int cntB = (nB < N_NODES) ? min(deg[curIdx(aB)], CAP) : 0;
    int nl = csr[(lane < 32 ? nA : aB) * CAP + (lane & 31)];
    int r = lane >> 3, c = lane & 7;
    float accA[8] = {}, accB[8] = {};
    int mx = max(cntA, cntB);
    for (int b = 0; b < mx; b += 16) {
        #pragma unroll
        for (int u = 0; u < 2; ++u) {
            int e = b + u * 8 + r;
            int sA = __shfl(nl, min(e, cntA - 1) & 31, 64);
            int sB = __shfl(nl, 32 + (min(e, cntB - 1) & 31), 64);
            bf16x8 vA = {}, vB = {};
            if (e < cntA) vA = *(const bf16x8*)(A1 + (size_t)sA * 256 + c * 8);
            if (e < cntB) vB = *(const bf16x8*)(A1 + (size_t)sB * 256 + c * 8);
            #pragma unroll
            for (int j = 0; j < 8; ++j) {
                accA[j] += bf2f((unsigned short)vA[j]);
                accB[j] += bf2f((unsigned short)vB[j]);
            }
        }
    }
    #pragma unroll
    for (int j = 0; j < 8; ++j) {
        accA[j] += __shfl_xor(accA[j], 8, 64);
        accA[j] += __shfl_xor(accA[j], 16, 64);
        accA[j] += __shfl_xor(accA[j], 32, 64);
        accB[j] += __shfl_xor(accB[j], 8, 64);
        accB[j] += __shfl_xor(accB[j], 16, 64);
        accB[j] += __shfl_xor(accB[j], 32, 64);
    }
    if (lane < 5) {   // cols c*8..c*8+7, all < 40
        float invA = 1.0f / fmaxf((float)cntA, 1.0f);
        const float* RrowA = (const float*)(A1 + (size_t)nA * 256 + 128);
        float o[8];
        #pragma unroll
        for (int j = 0; j < 8; ++j)
            o[j] = accA[j] * invA + RrowA[c * 8 + j] + b2[c * 8 + j];
        float* opA = out + (size_t)nA * CLASSES + c * 8;
        *(float4*)(opA)     = make_float4(o[0], o[1], o[2], o[3]);
        *(float4*)(opA + 4) = make_float4(o[4], o[5], o[6], o[7]);
        if (nB < N_NODES) {
            float invB = 1.0f / fmaxf((float)cntB, 1.0f);
            const float* RrowB = (const float*)(A1 + (size_t)nB * 256 + 128);
            #pragma unroll
            for (int j = 0; j < 8; ++j)
                o[j] = accB[j] * invB + RrowB[c * 8 + j] + b2[c * 8 + j];
            float* opB = out + (size_t)nB * CLASSES + c * 8;
            *(float4*)(opB)     = make_float4(o[0], o[1], o[2], o[3]);
            *(float4*)(opB + 4) = make_float4(o[4], o[5], o[6], o[7]);
        }
    }
}

extern "C" void kernel_launch(void* const* d_in, const int* in_sizes, int n_in,
                              void* d_out, int out_size, void* d_ws, size_t ws_size,
                              hipStream_t stream) {
    const float* x   = (const float*)d_in[0];
    const int*   ei  = (const int*)d_in[1];
    const float* W1l = (const float*)d_in[2];
    const float* W1r = (const float*)d_in[3];
    const float* b1  = (const float*)d_in[4];
    const float* W2l = (const float*)d_in[5];
    const float* W2r = (const float*)d_in[6];
    const float* b2  = (const float*)d_in[7];
    float* out = (float*)d_out;

    const int* src = ei;
    const int* dst = ei + N_EDGES;

    char* ws = (char*)d_ws;
    size_t off = 0;
    auto alloc = [&](size_t bytes) { void* p = ws + off; off += (bytes + 511) & ~(size_t)511; return p; };
    int* cur = (int*)alloc((size_t)NSH * CUR_STRIDE * 4);              // sharded degree/cursor
    int* csr = (int*)alloc((size_t)N_NODES * CAP * 4);                 // padded CSR (12.8 MB)
    unsigned short* Bp1 = (unsigned short*)alloc((size_t)32 * 128 * 8 * 2);
    unsigned short* Bp2 = (unsigned short*)alloc((size_t)16 * 128 * 8 * 2);
    unsigned short* A1  = (unsigned short*)alloc((size_t)N_NODES * 256 * 2);  // [mean|x] -> [P|R]

    hipMemsetAsync(cur, 0, (size_t)NSH * CUR_STRIDE * 4, stream);

    k_prep<<<BIN_B + CAST_B + PACK_B, 256, 0, stream>>>(
        src, dst, cur, csr, x, A1, W1l, W1r, Bp1, W2l, W2r, Bp2);

    k_agg1<<<(N_NODES / 2 + 3) / 4, 256, 0, stream>>>(A1, cur, csr);
    k_gemm<<<(N_NODES + 63) / 64, 256, 0, stream>>>(A1, Bp1, b1, Bp2);
    k_agg2<<<(N_NODES / 2 + 3) / 4, 256, 0, stream>>>(A1, cur, csr, b2, out);
}

// Round 5
// 254.767 us; speedup vs baseline: 1.1053x; 1.0604x over previous
//
#include <hip/hip_runtime.h>
#include <hip/hip_bf16.h>

#define N_NODES 100000
#define N_EDGES 800000
#define IN_DIM  128
#define HIDDEN  128
#define CLASSES 40
#define CAP     32          // max degree supported (Poisson(8): P(>32) ~ 3e-11/node)
#define NSH     8           // shards == XCDs
#define SLICES  400
#define EPB     2000        // edges per slice (SLICES*EPB == N_EDGES)
#define BIN_B   (NSH*SLICES)  // 3200 binning blocks: blk&7 = shard, blk>>3 = slice
#define CAST_B  12500       // 100000*32/256
#define PACK_B  24          // (4096+2048)/256
#define CUR_STRIDE 12544    // per-shard counter stride (ints, 16-aligned -> shard-pure lines)

typedef __attribute__((ext_vector_type(8))) short bf16x8;
typedef __attribute__((ext_vector_type(4))) float floatx4;

__device__ __forceinline__ float bf2f(unsigned short u) {
    return __uint_as_float(((unsigned int)u) << 16);
}
__device__ __forceinline__ unsigned short f2bf(float f) {
    unsigned int u = __float_as_uint(f);
    unsigned int r = 0x7fffu + ((u >> 16) & 1u);   // RNE
    return (unsigned short)((u + r) >> 16);
}
__device__ __forceinline__ int curIdx(int d) { return (d & 7) * CUR_STRIDE + (d >> 3); }

// ================= prep: bin + cast_x + pack1 + pack2 in one launch =================
// Binning is XCD-sharded: block (blk&7) only bins edges with (dst&7)==shard, and
// blockIdx%8 round-robins onto XCDs -> cur/csr lines stay in ONE XCD's L2
// (local atomics, write-merged csr lines). Correctness does not depend on the mapping.
// 400 slices: short per-thread atomic chains, 4x binning TLP; re-reads are L2/L3-served.
__global__ void k_prep(const int* __restrict__ src, const int* __restrict__ dst,
                       int* __restrict__ cur, int* __restrict__ csr,
                       const float* __restrict__ x, unsigned short* __restrict__ A1,
                       const float* __restrict__ W1l, const float* __restrict__ W1r,
                       unsigned short* __restrict__ Bp1,
                       const float* __restrict__ W2l, const float* __restrict__ W2r,
                       unsigned short* __restrict__ Bp2) {
    int blk = blockIdx.x;
    if (blk < BIN_B) {
        int g = blk & 7;            // shard (== XCD up to constant rotation)
        int slice = blk >> 3;
        const int4* s4p = reinterpret_cast<const int4*>(src) + slice * (EPB / 4);
        const int4* d4p = reinterpret_cast<const int4*>(dst) + slice * (EPB / 4);
        for (int i = threadIdx.x; i < EPB / 4; i += 256) {
            int4 d4 = d4p[i];
            int4 s4 = s4p[i];
            #pragma unroll
            for (int j = 0; j < 4; ++j) {
                int d = (&d4.x)[j];
                if ((d & 7) == g) {
                    int s = (&s4.x)[j];
                    int slot = atomicAdd(&cur[g * CUR_STRIDE + (d >> 3)], 1);
                    if (slot < CAP) csr[d * CAP + slot] = s;
                }
            }
        }
    } else if (blk < BIN_B + CAST_B) {
        // ---- x f32 -> bf16 into A1 cols 128..255 ----
        int t = (blk - BIN_B) * 256 + threadIdx.x;
        int n = t >> 5, g = t & 31;
        float4 v = reinterpret_cast<const float4*>(x + (size_t)n * 128)[g];
        ushort4 u = { f2bf(v.x), f2bf(v.y), f2bf(v.z), f2bf(v.w) };
        *(ushort4*)(A1 + (size_t)n * 256 + 128 + g * 4) = u;
    } else {
        int t = (blk - BIN_B - CAST_B) * 256 + threadIdx.x;
        if (t < 4096) {
            // ---- pack W1l/W1r -> Bp1[o 0..31][n 0..127][8] ----
            int o = t >> 7, n = t & 127;
            const float* W = (o < 16) ? W1l : W1r;
            int k0 = (o & 15) * 8;
            union { unsigned short us[8]; uint4 v; } pk;
            #pragma unroll
            for (int j = 0; j < 8; ++j) pk.us[j] = f2bf(W[(size_t)(k0 + j) * 128 + n]);
            *(uint4*)(Bp1 + (size_t)t * 8) = pk.v;
        } else {
            // ---- pack W2l/W2r -> Bp2[o 0..15][n 0..127][8]: n<64 W2l, n>=64 W2r ----
            int t2 = t - 4096;
            int o = t2 >> 7, n = t2 & 127;
            const float* W = (n < 64) ? W2l : W2r;
            int col = n & 63;
            int k0 = o * 8;
            union { unsigned short us[8]; uint4 v; } pk;
            #pragma unroll
            for (int j = 0; j < 8; ++j)
                pk.us[j] = (col < 40) ? f2bf(W[(size_t)(k0 + j) * 40 + col]) : (unsigned short)0;
            *(uint4*)(Bp2 + (size_t)t2 * 8) = pk.v;
        }
    }
}

// ================= gather-mean layer 1: 1 node/wave (TLP-max, round-2 form) =========
// wave/node; neighbor list cached in regs; shfl HOISTED out of divergent branch
// (ds_bpermute returns 0 from EXEC=0 source lanes -> must keep whole wave active).
__global__ void k_agg1(unsigned short* __restrict__ A1, const int* __restrict__ deg,
                       const int* __restrict__ csr) {
    int n = blockIdx.x * 4 + (threadIdx.x >> 6);
    int lane = threadIdx.x & 63;
    if (n >= N_NODES) return;
    int cnt = min(deg[curIdx(n)], CAP);
    int nl = csr[n * CAP + (lane & (CAP - 1))];   // lanes 32..63 mirror 0..31
    int r = lane >> 4, c = lane & 15;
    float acc[8] = {0.f, 0.f, 0.f, 0.f, 0.f, 0.f, 0.f, 0.f};
    for (int base = 0; base < cnt; base += 16) {
        #pragma unroll
        for (int u = 0; u < 4; ++u) {
            int e = base + u * 4 + r;
            int s = __shfl(nl, min(e, cnt - 1) & 31, 64);   // whole wave active here
            bf16x8 v = {};
            if (e < cnt)
                v = *(const bf16x8*)(A1 + (size_t)s * 256 + 128 + c * 8);
            #pragma unroll
            for (int j = 0; j < 8; ++j) acc[j] += bf2f((unsigned short)v[j]);
        }
    }
    #pragma unroll
    for (int j = 0; j < 8; ++j) {
        acc[j] += __shfl_xor(acc[j], 16, 64);
        acc[j] += __shfl_xor(acc[j], 32, 64);
    }
    if (lane < 16) {
        float inv = 1.0f / fmaxf((float)cnt, 1.0f);
        union { unsigned short us[8]; bf16x8 v; } pk;
        #pragma unroll
        for (int j = 0; j < 8; ++j) pk.us[j] = f2bf(acc[j] * inv);
        *(bf16x8*)(A1 + (size_t)n * 256 + c * 8) = pk.v;
    }
}

// ================= fused MFMA: h=relu([mean|x]@Wp1+b1); P|R = h@Wp2 =================
__global__ __launch_bounds__(256)
void k_gemm(unsigned short* __restrict__ A1, const unsigned short* __restrict__ Bp1,
            const float* __restrict__ b1, const unsigned short* __restrict__ Bp2) {
    __shared__ unsigned short Hs[4][16][136];
    int wv = threadIdx.x >> 6, lane = threadIdx.x & 63;
    int q = lane >> 4, nn = lane & 15;
    int m0 = blockIdx.x * 64 + wv * 16;
    int ma = m0 + nn;
    bool mv = (ma < N_NODES);
    const unsigned short* arow = A1 + (size_t)ma * 256;

    // phase A: [mean|x] @ Bp1, K=256
    floatx4 acc[8] = {};
    for (int kt = 0; kt < 8; ++kt) {
        bf16x8 a = {};
        if (mv) a = *(const bf16x8*)(arow + kt * 32 + q * 8);
        bf16x8 b[8];
        #pragma unroll
        for (int nt = 0; nt < 8; ++nt)
            b[nt] = *(const bf16x8*)(Bp1 + ((size_t)((kt * 4 + q) * 128 + nt * 16 + nn)) * 8);
        #pragma unroll
        for (int nt = 0; nt < 8; ++nt)
            acc[nt] = __builtin_amdgcn_mfma_f32_16x16x32_bf16(a, b[nt], acc[nt], 0, 0, 0);
    }
    // epilogue A: relu + bias -> LDS (wave-local tile; per-wave DS ops are in-order)
    #pragma unroll
    for (int nt = 0; nt < 8; ++nt) {
        int col = nt * 16 + nn;
        float bias = b1[col];
        #pragma unroll
        for (int r = 0; r < 4; ++r)
            Hs[wv][q * 4 + r][col] = f2bf(fmaxf(acc[nt][r] + bias, 0.f));
    }
    // phase B: h @ Bp2, K=128 -> P (cols 0..63) | R (cols 64..127)
    floatx4 acc2[8] = {};
    for (int kt = 0; kt < 4; ++kt) {
        bf16x8 a = *(const bf16x8*)(&Hs[wv][nn][kt * 32 + q * 8]);
        bf16x8 b[8];
        #pragma unroll
        for (int nt = 0; nt < 8; ++nt)
            b[nt] = *(const bf16x8*)(Bp2 + ((size_t)((kt * 4 + q) * 128 + nt * 16 + nn)) * 8);
        #pragma unroll
        for (int nt = 0; nt < 8; ++nt)
            acc2[nt] = __builtin_amdgcn_mfma_f32_16x16x32_bf16(a, b[nt], acc2[nt], 0, 0, 0);
    }
    // epilogue B: P bf16 cols 0..63; R f32 at byte offset 256 of each 512B row
    #pragma unroll
    for (int nt = 0; nt < 4; ++nt) {
        int col = nt * 16 + nn;
        #pragma unroll
        for (int r = 0; r < 4; ++r) {
            int ro = m0 + q * 4 + r;
            if (ro < N_NODES)
                A1[(size_t)ro * 256 + col] = f2bf(acc2[nt][r]);
        }
    }
    #pragma unroll
    for (int nt = 4; nt < 8; ++nt) {
        int col = (nt - 4) * 16 + nn;
        #pragma unroll
        for (int r = 0; r < 4; ++r) {
            int ro = m0 + q * 4 + r;
            if (ro < N_NODES) {
                float* Rp = (float*)(A1 + (size_t)ro * 256 + 128);
                Rp[col] = acc2[nt][r];
            }
        }
    }
}

// ========== gather-mean layer 2: 1 node/wave (round-2 form) + fused output ==========
__global__ void k_agg2(const unsigned short* __restrict__ A1, const int* __restrict__ deg,
                       const int* __restrict__ csr, const float* __restrict__ b2,
                       float* __restrict__ out) {
    int n = blockIdx.x * 4 + (threadIdx.x >> 6);
    int lane = threadIdx.x & 63;
    if (n >= N_NODES) return;
    int cnt = min(deg[curIdx(n)], CAP);
    int nl = csr[n * CAP + (lane & (CAP - 1))];   // lanes 32..63 mirror 0..31
    int r = lane >> 3, c = lane & 7;
    float acc[8] = {0.f, 0.f, 0.f, 0.f, 0.f, 0.f, 0.f, 0.f};
    for (int base = 0; base < cnt; base += 16) {
        #pragma unroll
        for (int u = 0; u < 2; ++u) {
            int e = base + u * 8 + r;
            int s = __shfl(nl, min(e, cnt - 1) & 31, 64);   // whole wave active here
            bf16x8 v = {};
            if (e < cnt)
                v = *(const bf16x8*)(A1 + (size_t)s * 256 + c * 8);
            #pragma unroll
            for (int j = 0; j < 8; ++j) acc[j] += bf2f((unsigned short)v[j]);
        }
    }
    #pragma unroll
    for (int j = 0; j < 8; ++j) {
        acc[j] += __shfl_xor(acc[j], 8, 64);
        acc[j] += __shfl_xor(acc[j], 16, 64);
        acc[j] += __shfl_xor(acc[j], 32, 64);
    }
    if (lane < 5) {   // cols c*8..c*8+7, all < 40
        float inv = 1.0f / fmaxf((float)cnt, 1.0f);
        const float* Rrow = (const float*)(A1 + (size_t)n * 256 + 128);
        float o[8];
        #pragma unroll
        for (int j = 0; j < 8; ++j)
            o[j] = acc[j] * inv + Rrow[c * 8 + j] + b2[c * 8 + j];
        float* op = out + (size_t)n * CLASSES + c * 8;
        *(float4*)(op)     = make_float4(o[0], o[1], o[2], o[3]);
        *(float4*)(op + 4) = make_float4(o[4], o[5], o[6], o[7]);
    }
}

extern "C" void kernel_launch(void* const* d_in, const int* in_sizes, int n_in,
                              void* d_out, int out_size, void* d_ws, size_t ws_size,
                              hipStream_t stream) {
    const float* x   = (const float*)d_in[0];
    const int*   ei  = (const int*)d_in[1];
    const float* W1l = (const float*)d_in[2];
    const float* W1r = (const float*)d_in[3];
    const float* b1  = (const float*)d_in[4];
    const float* W2l = (const float*)d_in[5];
    const float* W2r = (const float*)d_in[6];
    const float* b2  = (const float*)d_in[7];
    float* out = (float*)d_out;

    const int* src = ei;
    const int* dst = ei + N_EDGES;

    char* ws = (char*)d_ws;
    size_t off = 0;
    auto alloc = [&](size_t bytes) { void* p = ws + off; off += (bytes + 511) & ~(size_t)511; return p; };
    int* cur = (int*)alloc((size_t)NSH * CUR_STRIDE * 4);              // sharded degree/cursor
    int* csr = (int*)alloc((size_t)N_NODES * CAP * 4);                 // padded CSR (12.8 MB)
    unsigned short* Bp1 = (unsigned short*)alloc((size_t)32 * 128 * 8 * 2);
    unsigned short* Bp2 = (unsigned short*)alloc((size_t)16 * 128 * 8 * 2);
    unsigned short* A1  = (unsigned short*)alloc((size_t)N_NODES * 256 * 2);  // [mean|x] -> [P|R]

    hipMemsetAsync(cur, 0, (size_t)NSH * CUR_STRIDE * 4, stream);

    k_prep<<<BIN_B + CAST_B + PACK_B, 256, 0, stream>>>(
        src, dst, cur, csr, x, A1, W1l, W1r, Bp1, W2l, W2r, Bp2);

    k_agg1<<<(N_NODES + 3) / 4, 256, 0, stream>>>(A1, cur, csr);
    k_gemm<<<(N_NODES + 63) / 64, 256, 0, stream>>>(A1, Bp1, b1, Bp2);
    k_agg2<<<(N_NODES + 3) / 4, 256, 0, stream>>>(A1, cur, csr, b2, out);
}